// Round 8
// baseline (115.360 us; speedup 1.0000x reference)
//
#include <hip/hip_runtime.h>

// CompoundClassifier, round 8: r7 minus fat.
//   P = x_ing @ W1[:128], Q = x_cmp @ W1[128:] + b1  -> fp8 e4m3 tables (3.84 MB)
//   out[e] = sigmoid( relu(P[s]+Q[d]) . W2 + b2 )
// Changes vs r7 (each evidence-backed):
//   1. cvt_w dropped — r5 vs r6 showed in-pq f32 W1 frag loads are neutral
//      (L2-broadcast-hot) and the extra launch cost +3.4us.
//   2. edge inner math on float2 vectors -> v_pk_{add,max,fma}_f32 (VOP3P),
//      ~64 -> ~40 VALU/pass. Decode stays the r7-proven cvt_pk_f32_fp8.

#define H  128
#define NI 20000
#define NC 10000
#define NE 1000000

typedef _Float16 half8   __attribute__((ext_vector_type(8)));
typedef float    floatx2 __attribute__((ext_vector_type(2)));
typedef float    floatx4 __attribute__((ext_vector_type(4)));

// ws byte layout: just the two fp8 tables
#define P8_OFF 0
#define Q8_OFF (NI * H)        // 2,560,000

#define PB (NI / 16)   // 1250
#define QB (NC / 16)   // 625

#if __has_builtin(__builtin_amdgcn_cvt_pk_f32_fp8) && __has_builtin(__builtin_amdgcn_cvt_pk_fp8_f32)
#define HW_FP8 1
#else
#define HW_FP8 0
__device__ inline unsigned char enc_e4m3(float x) {
    unsigned s = x < 0.0f ? 0x80u : 0u;
    float a = fminf(fabsf(x), 448.0f);
    if (a < 0.0009765625f) return (unsigned char)s;
    int e; float m = frexpf(a, &e);
    int E = e + 6;
    if (E <= 0) {
        int f = (int)rintf(a * 512.0f);
        if (f > 7) return (unsigned char)(s | 0x08);
        return (unsigned char)(s | f);
    }
    int f = (int)rintf((m * 2.0f - 1.0f) * 8.0f);
    if (f == 8) { f = 0; ++E; }
    if (E > 15 || (E == 15 && f > 6)) { E = 15; f = 6; }
    return (unsigned char)(s | (E << 3) | f);
}
__device__ inline float dec_e4m3(unsigned char b) {
    int E = (b >> 3) & 15, f = b & 7;
    float v = (E == 0) ? (float)f * 0.001953125f
                       : (float)(8 + f) * exp2f((float)(E - 10));
    return (b & 0x80) ? -v : v;
}
#endif

// ---- P/Q precompute: 16x16x32 f16 MFMA (layouts verified r1/r3), fp8 epilogue ----
__launch_bounds__(256)
__global__ void pq_gemm(const float* __restrict__ xin,
                        const float* __restrict__ xcmp,
                        const float* __restrict__ W1,   // [256][128] row-major
                        const float* __restrict__ b1,
                        unsigned char* __restrict__ wsb) {
    const int b    = blockIdx.x;
    const bool isQ = (b >= PB);
    const int  rb  = (isQ ? b - PB : b) * 16;
    const float* X = isQ ? xcmp : xin;
    const int kofs = isQ ? H : 0;
    unsigned char* OUT8 = wsb + (isQ ? Q8_OFF : P8_OFF);

    const int lane = threadIdx.x & 63;
    const int w    = threadIdx.x >> 6;
    const int quad = lane >> 4;
    const int m    = lane & 15;

    // B-fragments from f32 W1 directly (L2-broadcast-hot across 1875 blocks;
    // r5-vs-r6 A/B showed this is neutral vs a pre-converted table)
    half8 bf[2][4];
    float b1v[2];
#pragma unroll
    for (int nt = 0; nt < 2; ++nt) {
        const int n = w * 32 + nt * 16 + m;
#pragma unroll
        for (int ks = 0; ks < 4; ++ks) {
            const int k0 = kofs + ks * 32 + quad * 8;
#pragma unroll
            for (int j = 0; j < 8; ++j)
                bf[nt][ks][j] = (_Float16)W1[(k0 + j) * H + n];
        }
        b1v[nt] = isQ ? b1[n] : 0.0f;
    }

    // A-fragments: row rb+m, contiguous 8 floats -> half8
    half8 af[4];
    const float* xr = X + (long)(rb + m) * H + quad * 8;
#pragma unroll
    for (int ks = 0; ks < 4; ++ks) {
        float4 a = *(const float4*)(xr + ks * 32);
        float4 c = *(const float4*)(xr + ks * 32 + 4);
        half8 v = { (_Float16)a.x, (_Float16)a.y, (_Float16)a.z, (_Float16)a.w,
                    (_Float16)c.x, (_Float16)c.y, (_Float16)c.z, (_Float16)c.w };
        af[ks] = v;
    }

    floatx4 acc[2] = { (floatx4)0.0f, (floatx4)0.0f };
#pragma unroll
    for (int ks = 0; ks < 4; ++ks)
#pragma unroll
        for (int nt = 0; nt < 2; ++nt)
            acc[nt] = __builtin_amdgcn_mfma_f32_16x16x32_f16(af[ks], bf[nt][ks], acc[nt], 0, 0, 0);

    // epilogue: +b1, fp8-encode, byte stores (C/D: col=lane&15, row=quad*4+r)
#pragma unroll
    for (int nt = 0; nt < 2; ++nt) {
        const int col = w * 32 + nt * 16 + m;
#pragma unroll
        for (int r = 0; r < 4; ++r) {
            const float v = acc[nt][r] + b1v[nt];
#if HW_FP8
            const unsigned u = (unsigned)__builtin_amdgcn_cvt_pk_fp8_f32(v, v, 0, false);
            OUT8[(rb + quad * 4 + r) * H + col] = (unsigned char)(u & 0xff);
#else
            OUT8[(rb + quad * 4 + r) * H + col] = enc_e4m3(v);
#endif
        }
    }
}

// ---- edge kernel: 8 lanes/edge, fp8 rows, HW pk decode, packed-f32 math ----
#define EGRID 2048

__launch_bounds__(256)
__global__ void edge_mlp(const unsigned char* __restrict__ wsb,
                         const int* __restrict__ src_idx,
                         const int* __restrict__ dst_idx,
                         const float* __restrict__ W2,
                         const float* __restrict__ b2p,
                         float* __restrict__ out) {
    const int tid  = threadIdx.x;
    const int c    = tid & 7;       // 16-byte slice of the 128-B row
    const int slot = tid >> 3;      // edge within pass (0..31)

    // W2 slice as 8 packed float2 (cols c*16 .. c*16+15)
    floatx2 w2v[8];
#pragma unroll
    for (int i = 0; i < 8; ++i) {
        w2v[i][0] = W2[c * 16 + 2 * i];
        w2v[i][1] = W2[c * 16 + 2 * i + 1];
    }
    const float b2v = b2p[0];

    const unsigned char* P8 = wsb + P8_OFF;
    const unsigned char* Q8 = wsb + Q8_OFF;

    int e  = blockIdx.x * 32 + slot;
    int si = 0, di = 0;
    if (e < NE) { si = src_idx[e]; di = dst_idx[e]; }

    while (e < NE) {
        const uint4 pd = *(const uint4*)(P8 + si * H + c * 16);
        const uint4 qd = *(const uint4*)(Q8 + di * H + c * 16);

        // prefetch next pass's indices while row loads are in flight
        const int e2 = e + 32 * EGRID;
        int si2 = 0, di2 = 0;
        if (e2 < NE) { si2 = src_idx[e2]; di2 = dst_idx[e2]; }

        const unsigned pw[4] = { pd.x, pd.y, pd.z, pd.w };
        const unsigned qw[4] = { qd.x, qd.y, qd.z, qd.w };

        floatx2 acc2 = { 0.0f, 0.0f };
        const floatx2 z2 = { 0.0f, 0.0f };
#pragma unroll
        for (int jw = 0; jw < 4; ++jw) {
#if HW_FP8
            floatx2 pl = __builtin_amdgcn_cvt_pk_f32_fp8((int)pw[jw], false);
            floatx2 ph = __builtin_amdgcn_cvt_pk_f32_fp8((int)pw[jw], true);
            floatx2 ql = __builtin_amdgcn_cvt_pk_f32_fp8((int)qw[jw], false);
            floatx2 qh = __builtin_amdgcn_cvt_pk_f32_fp8((int)qw[jw], true);
#else
            floatx2 pl = { dec_e4m3(pw[jw] & 0xff), dec_e4m3((pw[jw] >> 8) & 0xff) };
            floatx2 ph = { dec_e4m3((pw[jw] >> 16) & 0xff), dec_e4m3(pw[jw] >> 24) };
            floatx2 ql = { dec_e4m3(qw[jw] & 0xff), dec_e4m3((qw[jw] >> 8) & 0xff) };
            floatx2 qh = { dec_e4m3((qw[jw] >> 16) & 0xff), dec_e4m3(qw[jw] >> 24) };
#endif
            // packed f32: v_pk_add_f32 / v_pk_max_f32 / v_pk_fma_f32
            floatx2 hl = pl + ql;
            floatx2 hh = ph + qh;
#if __has_builtin(__builtin_elementwise_max)
            hl = __builtin_elementwise_max(hl, z2);
            hh = __builtin_elementwise_max(hh, z2);
#else
            hl[0] = fmaxf(hl[0], 0.0f); hl[1] = fmaxf(hl[1], 0.0f);
            hh[0] = fmaxf(hh[0], 0.0f); hh[1] = fmaxf(hh[1], 0.0f);
#endif
            acc2 += hl * w2v[2 * jw];
            acc2 += hh * w2v[2 * jw + 1];
        }
        float acc = acc2[0] + acc2[1];

        // reduce over the 8-lane edge group
        acc += __shfl_xor(acc, 1);
        acc += __shfl_xor(acc, 2);
        acc += __shfl_xor(acc, 4);

        if (c == 0)
            out[e] = 1.0f / (1.0f + expf(-(acc + b2v)));

        e = e2; si = si2; di = di2;
    }
}

extern "C" void kernel_launch(void* const* d_in, const int* in_sizes, int n_in,
                              void* d_out, int out_size, void* d_ws, size_t ws_size,
                              hipStream_t stream) {
    const float* xin  = (const float*)d_in[0];
    const float* xcmp = (const float*)d_in[1];
    const int*   eidx = (const int*)d_in[2];    // [2,E]: first E src, next E dst
    const float* W1   = (const float*)d_in[3];
    const float* b1   = (const float*)d_in[4];
    const float* W2   = (const float*)d_in[5];
    const float* b2   = (const float*)d_in[6];
    float* out = (float*)d_out;
    unsigned char* wsb = (unsigned char*)d_ws;  // 3.84 MB used

    hipLaunchKernelGGL(pq_gemm, dim3(PB + QB), dim3(256), 0, stream,
                       xin, xcmp, W1, b1, wsb);
    hipLaunchKernelGGL(edge_mlp, dim3(EGRID), dim3(256), 0, stream,
                       wsb, eidx, eidx + NE, W2, b2, out);
}